// Round 1
// baseline (390.717 us; speedup 1.0000x reference)
//
#include <hip/hip_runtime.h>
#include <cstdint>

#define N_NODES 50000
#define IN_DIM 256
#define OUT_DIM 512
#define NUM_HASH 8
#define HASH_DIM 256
#define N_EDGES 800000

typedef unsigned short ushort_t;
typedef __attribute__((ext_vector_type(8))) short short8;
typedef __attribute__((ext_vector_type(4))) float f32x4;

__device__ __forceinline__ ushort_t f2bf(float f) {
  uint32_t u = __builtin_bit_cast(uint32_t, f);
  u = (u + 0x7fffu + ((u >> 16) & 1u)) >> 16;
  return (ushort_t)u;
}
__device__ __forceinline__ float bf2f(uint32_t u) {
  return __builtin_bit_cast(float, u << 16);
}

__device__ __forceinline__ void gload_lds16(const void* g, void* l) {
  __builtin_amdgcn_global_load_lds((const __attribute__((address_space(1))) void*)g,
                                   (__attribute__((address_space(3))) void*)l, 16, 0, 0);
}

// ---- convert x (f32) -> x_bf (bf16), 4 elems/thread ----
__global__ void cvt_x_kernel(const float* __restrict__ x, ushort_t* __restrict__ xbf) {
  int g = blockIdx.x * 256 + threadIdx.x;  // 3.2M threads, 4 floats each
  float4 v = reinterpret_cast<const float4*>(x)[g];
  uint2 pack;
  pack.x = (uint32_t)f2bf(v.x) | ((uint32_t)f2bf(v.y) << 16);
  pack.y = (uint32_t)f2bf(v.z) | ((uint32_t)f2bf(v.w) << 16);
  *reinterpret_cast<uint2*>(xbf + (size_t)g * 4) = pack;
}

// ---- degree count ----
__global__ void deg_kernel(const int* __restrict__ dst, int* __restrict__ deg) {
  int e = blockIdx.x * 256 + threadIdx.x;
  atomicAdd(&deg[dst[e]], 1);
}

// ---- single-block exclusive scan over 50000 degrees ----
__global__ void scan_kernel(const int* __restrict__ deg, int* __restrict__ offsets,
                            int* __restrict__ cursor) {
  __shared__ int part[1024];
  const int t = threadIdx.x;
  const int chunk = (N_NODES + 1023) / 1024;  // 49
  const int lo = t * chunk;
  const int hi = min(lo + chunk, N_NODES);
  int s = 0;
  for (int i = lo; i < hi; ++i) s += deg[i];
  part[t] = s;
  __syncthreads();
  for (int d = 1; d < 1024; d <<= 1) {
    int v = part[t];
    int add = (t >= d) ? part[t - d] : 0;
    __syncthreads();
    part[t] = v + add;
    __syncthreads();
  }
  int run = (t == 0) ? 0 : part[t - 1];
  for (int i = lo; i < hi; ++i) {
    offsets[i] = run;
    cursor[i] = run;
    run += deg[i];
  }
  if (t == 1023) offsets[N_NODES] = run;
}

// ---- CSR fill ----
__global__ void fill_kernel(const int* __restrict__ src, const int* __restrict__ dst,
                            int* __restrict__ cursor, int* __restrict__ csr) {
  int e = blockIdx.x * 256 + threadIdx.x;
  int d = dst[e];
  int pos = atomicAdd(&cursor[d], 1);
  csr[pos] = src[e];
}

// ---- segment mean: one wave per node, 4 bf16/lane ----
__global__ void agg_kernel(const ushort_t* __restrict__ xbf, const int* __restrict__ offsets,
                           const int* __restrict__ csr, ushort_t* __restrict__ basebf) {
  int wid = (blockIdx.x * 256 + threadIdx.x) >> 6;
  int lane = threadIdx.x & 63;
  if (wid >= N_NODES) return;
  int off = offsets[wid], end = offsets[wid + 1];
  float a0 = 0.f, a1 = 0.f, a2 = 0.f, a3 = 0.f;
  for (int i = off; i < end; ++i) {
    int s = csr[i];
    uint2 v = *reinterpret_cast<const uint2*>(xbf + (size_t)s * IN_DIM + lane * 4);
    a0 += bf2f(v.x & 0xffffu);
    a1 += bf2f(v.x >> 16);
    a2 += bf2f(v.y & 0xffffu);
    a3 += bf2f(v.y >> 16);
  }
  int d = end - off;
  if (d > 0) {
    float inv = 1.0f / (float)d;
    a0 *= inv; a1 *= inv; a2 *= inv; a3 *= inv;
  } else {
    uint2 v = *reinterpret_cast<const uint2*>(xbf + (size_t)wid * IN_DIM + lane * 4);
    a0 = bf2f(v.x & 0xffffu);
    a1 = bf2f(v.x >> 16);
    a2 = bf2f(v.y & 0xffffu);
    a3 = bf2f(v.y >> 16);
  }
  uint2 o;
  o.x = (uint32_t)f2bf(a0) | ((uint32_t)f2bf(a1) << 16);
  o.y = (uint32_t)f2bf(a2) | ((uint32_t)f2bf(a3) << 16);
  *reinterpret_cast<uint2*>(basebf + (size_t)wid * IN_DIM + lane * 4) = o;
}

// ---- extract (col, sign) from signed one-hot hash mats ----
__global__ void extract_kernel(const float* __restrict__ hm, int* __restrict__ col,
                               float* __restrict__ sign) {
  const int t = blockIdx.x * 256 + threadIdx.x;  // 2048 = (h,i)
  const float* row = hm + (size_t)t * HASH_DIM;
  int c = 0;
  float s = 0.f;
  for (int j = 0; j < HASH_DIM; ++j) {
    float v = row[j];
    if (v != 0.f) { c = j; s = v; }
  }
  col[t] = c;
  sign[t] = s;
}

// ---- build combined B^T [OUT_DIM=512 rows][K=512 cols] in bf16 ----
// rows o; cols k: k<256 -> W_eff[k][o] = sum_h sign*W_post[h*256+col][o]; k>=256 -> W_self[k-256][o]
__global__ void build_wct_kernel(const float* __restrict__ Wpost, const float* __restrict__ Wself,
                                 const int* __restrict__ col, const float* __restrict__ sign,
                                 ushort_t* __restrict__ wct) {
  const int k = blockIdx.x;  // 0..511
#pragma unroll
  for (int t = 0; t < 2; ++t) {
    const int o = threadIdx.x + t * 256;
    float acc;
    if (k < 256) {
      acc = 0.f;
      for (int h = 0; h < NUM_HASH; ++h) {
        const int c = col[h * 256 + k];
        const float s = sign[h * 256 + k];
        acc += s * Wpost[(size_t)(h * 256 + c) * OUT_DIM + o];
      }
    } else {
      acc = Wself[(size_t)(k - 256) * OUT_DIM + o];
    }
    wct[(size_t)o * 512 + k] = f2bf(acc);
  }
}

// ---- fused GEMM: out = elu([base|x] @ [Weff;Wself] + bias), m97-style 128x128 tile ----
__global__ __launch_bounds__(256) void gemm_kernel(const ushort_t* __restrict__ Abase,
                                                   const ushort_t* __restrict__ Ax,
                                                   const ushort_t* __restrict__ Bt,
                                                   const float* __restrict__ bias,
                                                   float* __restrict__ out) {
  __shared__ __align__(16) ushort_t As[128 * 32];
  __shared__ __align__(16) ushort_t Bs[128 * 32];
  const int tid = threadIdx.x;
  const int lane = tid & 63;
  const int w = tid >> 6;
  const int bm = blockIdx.y, bn = blockIdx.x;
  const int wm = w & 1, wn = w >> 1;
  f32x4 acc[4][4] = {};

  for (int kt = 0; kt < 16; ++kt) {
    const ushort_t* Aptr = (kt < 8) ? Abase : Ax;
    const int k0 = (kt < 8) ? kt * 32 : kt * 32 - 256;
#pragma unroll
    for (int j = 0; j < 2; ++j) {
      const int c = (j * 4 + w) * 64 + lane;
      const int r = c >> 2, seg = c & 3;
      int rg = bm * 128 + r;
      rg = rg < N_NODES ? rg : N_NODES - 1;
      gload_lds16(Aptr + (size_t)rg * IN_DIM + k0 + seg * 8, &As[(j * 4 + w) * 512]);
      const int rb = bn * 128 + r;
      gload_lds16(Bt + (size_t)rb * 512 + kt * 32 + seg * 8, &Bs[(j * 4 + w) * 512]);
    }
    __syncthreads();
    short8 af[4], bfr[4];
#pragma unroll
    for (int i = 0; i < 4; ++i)
      af[i] = *reinterpret_cast<const short8*>(
          &As[(wm * 64 + i * 16 + (lane & 15)) * 32 + (lane >> 4) * 8]);
#pragma unroll
    for (int j = 0; j < 4; ++j)
      bfr[j] = *reinterpret_cast<const short8*>(
          &Bs[(wn * 64 + j * 16 + (lane & 15)) * 32 + (lane >> 4) * 8]);
#pragma unroll
    for (int i = 0; i < 4; ++i)
#pragma unroll
      for (int j = 0; j < 4; ++j)
        acc[i][j] = __builtin_amdgcn_mfma_f32_16x16x32_bf16(af[i], bfr[j], acc[i][j], 0, 0, 0);
    __syncthreads();
  }

  const int row0 = bm * 128 + wm * 64;
  const int col0 = bn * 128 + wn * 64;
#pragma unroll
  for (int j = 0; j < 4; ++j) {
    const int colg = col0 + j * 16 + (lane & 15);
    const float b = bias[colg];
#pragma unroll
    for (int i = 0; i < 4; ++i) {
#pragma unroll
      for (int r = 0; r < 4; ++r) {
        const int rowg = row0 + i * 16 + (lane >> 4) * 4 + r;
        if (rowg < N_NODES) {
          float v = acc[i][j][r] + b;
          out[(size_t)rowg * OUT_DIM + colg] = v > 0.f ? v : expm1f(v);
        }
      }
    }
  }
}

extern "C" void kernel_launch(void* const* d_in, const int* in_sizes, int n_in,
                              void* d_out, int out_size, void* d_ws, size_t ws_size,
                              hipStream_t stream) {
  const float* x = (const float*)d_in[0];
  const float* Wpost = (const float*)d_in[1];
  const float* Wself = (const float*)d_in[2];
  const float* bias = (const float*)d_in[3];
  const float* hm = (const float*)d_in[4];
  const int* esrc = (const int*)d_in[5];
  const int* edst = (const int*)d_in[6];
  float* out = (float*)d_out;

  char* ws = (char*)d_ws;
  ushort_t* xbf = (ushort_t*)ws;   ws += 25600000;   // 50000*256*2
  ushort_t* basebf = (ushort_t*)ws; ws += 25600000;  // 50000*256*2
  ushort_t* wct = (ushort_t*)ws;   ws += 524288;     // 512*512*2
  int* colb = (int*)ws;            ws += 8192;       // 2048*4
  float* signb = (float*)ws;       ws += 8192;       // 2048*4
  int* deg = (int*)ws;             ws += 200192;     // 50000*4 (padded)
  int* offsets = (int*)ws;         ws += 200192;     // 50001*4 (padded)
  int* cursor = (int*)ws;          ws += 200192;     // 50000*4 (padded)
  int* csr = (int*)ws;             ws += 3200000;    // 800000*4

  hipMemsetAsync(deg, 0, (size_t)N_NODES * 4, stream);
  cvt_x_kernel<<<12500, 256, 0, stream>>>(x, xbf);
  deg_kernel<<<3125, 256, 0, stream>>>(edst, deg);
  scan_kernel<<<1, 1024, 0, stream>>>(deg, offsets, cursor);
  fill_kernel<<<3125, 256, 0, stream>>>(esrc, edst, cursor, csr);
  agg_kernel<<<12500, 256, 0, stream>>>(xbf, offsets, csr, basebf);
  extract_kernel<<<8, 256, 0, stream>>>(hm, colb, signb);
  build_wct_kernel<<<512, 256, 0, stream>>>(Wpost, Wself, colb, signb, wct);
  dim3 ggrid(4, (N_NODES + 127) / 128);
  gemm_kernel<<<ggrid, 256, 0, stream>>>(basebf, xbf, wct, bias, out);
}

// Round 2
// 292.147 us; speedup vs baseline: 1.3374x; 1.3374x over previous
//
#include <hip/hip_runtime.h>
#include <cstdint>

#define N_NODES 50000
#define IN_DIM 256
#define OUT_DIM 512
#define NUM_HASH 8
#define HASH_DIM 256
#define N_EDGES 800000
#define SCAN_BLOCKS ((N_NODES + 255) / 256)  // 196

typedef unsigned short ushort_t;
typedef __attribute__((ext_vector_type(8))) short short8;
typedef __attribute__((ext_vector_type(4))) float f32x4;

__device__ __forceinline__ ushort_t f2bf(float f) {
  uint32_t u = __builtin_bit_cast(uint32_t, f);
  u = (u + 0x7fffu + ((u >> 16) & 1u)) >> 16;
  return (ushort_t)u;
}
__device__ __forceinline__ float bf2f(uint32_t u) {
  return __builtin_bit_cast(float, u << 16);
}

__device__ __forceinline__ void gload_lds16(const void* g, void* l) {
  __builtin_amdgcn_global_load_lds((const __attribute__((address_space(1))) void*)g,
                                   (__attribute__((address_space(3))) void*)l, 16, 0, 0);
}

// ---- convert x (f32) -> x_bf (bf16), 4 elems/thread ----
__global__ void cvt_x_kernel(const float* __restrict__ x, ushort_t* __restrict__ xbf) {
  int g = blockIdx.x * 256 + threadIdx.x;
  float4 v = reinterpret_cast<const float4*>(x)[g];
  uint2 pack;
  pack.x = (uint32_t)f2bf(v.x) | ((uint32_t)f2bf(v.y) << 16);
  pack.y = (uint32_t)f2bf(v.z) | ((uint32_t)f2bf(v.w) << 16);
  *reinterpret_cast<uint2*>(xbf + (size_t)g * 4) = pack;
}

// ---- degree count ----
__global__ void deg_kernel(const int* __restrict__ dst, int* __restrict__ deg) {
  int e = blockIdx.x * 256 + threadIdx.x;
  atomicAdd(&deg[dst[e]], 1);
}

// ---- scan phase 1: per-block (256-elem) sums ----
__global__ void scan_bsum_kernel(const int* __restrict__ deg, int* __restrict__ bsum) {
  __shared__ int ws[4];
  const int t = threadIdx.x;
  const int i = blockIdx.x * 256 + t;
  int v = (i < N_NODES) ? deg[i] : 0;
#pragma unroll
  for (int d = 1; d < 64; d <<= 1) v += __shfl_xor(v, d, 64);
  if ((t & 63) == 0) ws[t >> 6] = v;
  __syncthreads();
  if (t == 0) bsum[blockIdx.x] = ws[0] + ws[1] + ws[2] + ws[3];
}

// ---- scan phase 2: single block exclusive-scans the 196 block sums ----
__global__ void scan_bscan_kernel(const int* __restrict__ bsum, int* __restrict__ boff) {
  __shared__ int tmp[256];
  const int t = threadIdx.x;
  int v = (t < SCAN_BLOCKS) ? bsum[t] : 0;
  tmp[t] = v;
  __syncthreads();
#pragma unroll
  for (int d = 1; d < 256; d <<= 1) {
    int add = (t >= d) ? tmp[t - d] : 0;
    __syncthreads();
    tmp[t] += add;
    __syncthreads();
  }
  boff[t] = (t == 0) ? 0 : tmp[t - 1];
}

// ---- scan phase 3: per-block inclusive scan + base, write offsets & cursor ----
__global__ void scan_final_kernel(const int* __restrict__ deg, const int* __restrict__ boff,
                                  int* __restrict__ offsets, int* __restrict__ cursor) {
  __shared__ int tmp[256];
  const int t = threadIdx.x;
  const int i = blockIdx.x * 256 + t;
  int v = (i < N_NODES) ? deg[i] : 0;
  tmp[t] = v;
  __syncthreads();
#pragma unroll
  for (int d = 1; d < 256; d <<= 1) {
    int add = (t >= d) ? tmp[t - d] : 0;
    __syncthreads();
    tmp[t] += add;
    __syncthreads();
  }
  const int excl = tmp[t] - v + boff[blockIdx.x];
  if (i < N_NODES) {
    offsets[i] = excl;
    cursor[i] = excl;
  }
  if (i == 0) offsets[N_NODES] = N_EDGES;  // total degree == E by construction
}

// ---- CSR fill ----
__global__ void fill_kernel(const int* __restrict__ src, const int* __restrict__ dst,
                            int* __restrict__ cursor, int* __restrict__ csr) {
  int e = blockIdx.x * 256 + threadIdx.x;
  int d = dst[e];
  int pos = atomicAdd(&cursor[d], 1);
  csr[pos] = src[e];
}

// ---- segment mean: one wave per node, 4 bf16/lane ----
__global__ void agg_kernel(const ushort_t* __restrict__ xbf, const int* __restrict__ offsets,
                           const int* __restrict__ csr, ushort_t* __restrict__ basebf) {
  int wid = (blockIdx.x * 256 + threadIdx.x) >> 6;
  int lane = threadIdx.x & 63;
  if (wid >= N_NODES) return;
  int off = offsets[wid], end = offsets[wid + 1];
  float a0 = 0.f, a1 = 0.f, a2 = 0.f, a3 = 0.f;
  for (int i = off; i < end; ++i) {
    int s = csr[i];
    uint2 v = *reinterpret_cast<const uint2*>(xbf + (size_t)s * IN_DIM + lane * 4);
    a0 += bf2f(v.x & 0xffffu);
    a1 += bf2f(v.x >> 16);
    a2 += bf2f(v.y & 0xffffu);
    a3 += bf2f(v.y >> 16);
  }
  int d = end - off;
  if (d > 0) {
    float inv = 1.0f / (float)d;
    a0 *= inv; a1 *= inv; a2 *= inv; a3 *= inv;
  } else {
    uint2 v = *reinterpret_cast<const uint2*>(xbf + (size_t)wid * IN_DIM + lane * 4);
    a0 = bf2f(v.x & 0xffffu);
    a1 = bf2f(v.x >> 16);
    a2 = bf2f(v.y & 0xffffu);
    a3 = bf2f(v.y >> 16);
  }
  uint2 o;
  o.x = (uint32_t)f2bf(a0) | ((uint32_t)f2bf(a1) << 16);
  o.y = (uint32_t)f2bf(a2) | ((uint32_t)f2bf(a3) << 16);
  *reinterpret_cast<uint2*>(basebf + (size_t)wid * IN_DIM + lane * 4) = o;
}

// ---- extract (col, sign) from signed one-hot hash mats ----
__global__ void extract_kernel(const float* __restrict__ hm, int* __restrict__ col,
                               float* __restrict__ sign) {
  const int t = blockIdx.x * 256 + threadIdx.x;  // 2048 = (h,i)
  const float* row = hm + (size_t)t * HASH_DIM;
  int c = 0;
  float s = 0.f;
  for (int j = 0; j < HASH_DIM; ++j) {
    float v = row[j];
    if (v != 0.f) { c = j; s = v; }
  }
  col[t] = c;
  sign[t] = s;
}

// ---- build combined B^T [OUT=512 rows][K=512 cols] bf16 ----
__global__ void build_wct_kernel(const float* __restrict__ Wpost, const float* __restrict__ Wself,
                                 const int* __restrict__ col, const float* __restrict__ sign,
                                 ushort_t* __restrict__ wct) {
  const int k = blockIdx.x;  // 0..511
#pragma unroll
  for (int t = 0; t < 2; ++t) {
    const int o = threadIdx.x + t * 256;
    float acc;
    if (k < 256) {
      acc = 0.f;
      for (int h = 0; h < NUM_HASH; ++h) {
        const int c = col[h * 256 + k];
        const float s = sign[h * 256 + k];
        acc += s * Wpost[(size_t)(h * 256 + c) * OUT_DIM + o];
      }
    } else {
      acc = Wself[(size_t)(k - 256) * OUT_DIM + o];
    }
    wct[(size_t)o * 512 + k] = f2bf(acc);
  }
}

// ---- fused GEMM: out = elu([base|x] @ [Weff;Wself] + bias), 128x128 tile ----
__global__ __launch_bounds__(256) void gemm_kernel(const ushort_t* __restrict__ Abase,
                                                   const ushort_t* __restrict__ Ax,
                                                   const ushort_t* __restrict__ Bt,
                                                   const float* __restrict__ bias,
                                                   float* __restrict__ out) {
  __shared__ __align__(16) ushort_t As[128 * 32];
  __shared__ __align__(16) ushort_t Bs[128 * 32];
  const int tid = threadIdx.x;
  const int lane = tid & 63;
  const int w = tid >> 6;
  const int bm = blockIdx.y, bn = blockIdx.x;
  const int wm = w & 1, wn = w >> 1;
  f32x4 acc[4][4] = {};

  for (int kt = 0; kt < 16; ++kt) {
    const ushort_t* Aptr = (kt < 8) ? Abase : Ax;
    const int k0 = (kt < 8) ? kt * 32 : kt * 32 - 256;
#pragma unroll
    for (int j = 0; j < 2; ++j) {
      const int c = (j * 4 + w) * 64 + lane;
      const int r = c >> 2, seg = c & 3;
      int rg = bm * 128 + r;
      rg = rg < N_NODES ? rg : N_NODES - 1;
      gload_lds16(Aptr + (size_t)rg * IN_DIM + k0 + seg * 8, &As[(j * 4 + w) * 512]);
      const int rb = bn * 128 + r;
      gload_lds16(Bt + (size_t)rb * 512 + kt * 32 + seg * 8, &Bs[(j * 4 + w) * 512]);
    }
    __syncthreads();
    short8 af[4], bfr[4];
#pragma unroll
    for (int i = 0; i < 4; ++i)
      af[i] = *reinterpret_cast<const short8*>(
          &As[(wm * 64 + i * 16 + (lane & 15)) * 32 + (lane >> 4) * 8]);
#pragma unroll
    for (int j = 0; j < 4; ++j)
      bfr[j] = *reinterpret_cast<const short8*>(
          &Bs[(wn * 64 + j * 16 + (lane & 15)) * 32 + (lane >> 4) * 8]);
#pragma unroll
    for (int i = 0; i < 4; ++i)
#pragma unroll
      for (int j = 0; j < 4; ++j)
        acc[i][j] = __builtin_amdgcn_mfma_f32_16x16x32_bf16(af[i], bfr[j], acc[i][j], 0, 0, 0);
    __syncthreads();
  }

  const int row0 = bm * 128 + wm * 64;
  const int col0 = bn * 128 + wn * 64;
#pragma unroll
  for (int j = 0; j < 4; ++j) {
    const int colg = col0 + j * 16 + (lane & 15);
    const float b = bias[colg];
#pragma unroll
    for (int i = 0; i < 4; ++i) {
#pragma unroll
      for (int r = 0; r < 4; ++r) {
        const int rowg = row0 + i * 16 + (lane >> 4) * 4 + r;
        if (rowg < N_NODES) {
          float v = acc[i][j][r] + b;
          out[(size_t)rowg * OUT_DIM + colg] = v > 0.f ? v : expm1f(v);
        }
      }
    }
  }
}

extern "C" void kernel_launch(void* const* d_in, const int* in_sizes, int n_in,
                              void* d_out, int out_size, void* d_ws, size_t ws_size,
                              hipStream_t stream) {
  const float* x = (const float*)d_in[0];
  const float* Wpost = (const float*)d_in[1];
  const float* Wself = (const float*)d_in[2];
  const float* bias = (const float*)d_in[3];
  const float* hm = (const float*)d_in[4];
  const int* esrc = (const int*)d_in[5];
  const int* edst = (const int*)d_in[6];
  float* out = (float*)d_out;

  char* ws = (char*)d_ws;
  ushort_t* xbf = (ushort_t*)ws;   ws += 25600000;   // 50000*256*2
  ushort_t* basebf = (ushort_t*)ws; ws += 25600000;  // 50000*256*2
  ushort_t* wct = (ushort_t*)ws;   ws += 524288;     // 512*512*2
  int* colb = (int*)ws;            ws += 8192;       // 2048*4
  float* signb = (float*)ws;       ws += 8192;       // 2048*4
  int* deg = (int*)ws;             ws += 200192;     // 50000*4 (padded)
  int* offsets = (int*)ws;         ws += 200704;     // 50001*4 (padded)
  int* cursor = (int*)ws;          ws += 200192;     // 50000*4 (padded)
  int* bsum = (int*)ws;            ws += 1024;       // 196*4 (padded)
  int* boff = (int*)ws;            ws += 1024;       // 256*4
  int* csr = (int*)ws;             ws += 3200000;    // 800000*4

  hipMemsetAsync(deg, 0, (size_t)N_NODES * 4, stream);
  cvt_x_kernel<<<12500, 256, 0, stream>>>(x, xbf);
  deg_kernel<<<3125, 256, 0, stream>>>(edst, deg);
  scan_bsum_kernel<<<SCAN_BLOCKS, 256, 0, stream>>>(deg, bsum);
  scan_bscan_kernel<<<1, 256, 0, stream>>>(bsum, boff);
  scan_final_kernel<<<SCAN_BLOCKS, 256, 0, stream>>>(deg, boff, offsets, cursor);
  fill_kernel<<<3125, 256, 0, stream>>>(esrc, edst, cursor, csr);
  agg_kernel<<<12500, 256, 0, stream>>>(xbf, offsets, csr, basebf);
  extract_kernel<<<8, 256, 0, stream>>>(hm, colb, signb);
  build_wct_kernel<<<512, 256, 0, stream>>>(Wpost, Wself, colb, signb, wct);
  dim3 ggrid(4, (N_NODES + 127) / 128);
  gemm_kernel<<<ggrid, 256, 0, stream>>>(basebf, xbf, wct, bias, out);
}